// Round 6
// baseline (893.933 us; speedup 1.0000x reference)
//
#include <hip/hip_runtime.h>

#define INT_MAX_C 0x7fffffff

typedef __attribute__((ext_vector_type(8))) short s16x8;
typedef __attribute__((ext_vector_type(4))) float f32x4;

// ---------------------------------------------------------------- label prep
__global__ void k_init_inv(int* inv, int s) {
  int j = blockIdx.x * 256 + threadIdx.x;
  if (j < s) inv[j] = INT_MAX_C;
}

__global__ void k_scatter(const int* __restrict__ tyi, int* __restrict__ inv, int s) {
  int j = blockIdx.x * 256 + threadIdx.x;
  if (j < s) {
    int v = tyi[j];
    if (v >= 0 && v < s) atomicMin(&inv[v], j);
  }
}

__global__ void k_labels(const int* __restrict__ yi, const int* __restrict__ inv,
                         int* __restrict__ labels, int b, int s) {
  int i = blockIdx.x * 256 + threadIdx.x;
  if (i < b) {
    int v = yi[i];
    int lab = 0;
    if (v >= 0 && v < s) { int p = inv[v]; if (p != INT_MAX_C) lab = p; }
    labels[i] = lab;
  }
}

// ---------------------------------------------------------------- Y norms (fallback path)
__global__ __launch_bounds__(256) void k_ynorm(const float* __restrict__ Y,
                                               float* __restrict__ invY, int f) {
  int j = blockIdx.x;
  const float* row = Y + (size_t)j * f;
  float ss = 0.f;
  for (int k = threadIdx.x * 4; k < f; k += 256 * 4) {
    float4 v = *(const float4*)(row + k);
    ss += v.x * v.x + v.y * v.y + v.z * v.z + v.w * v.w;
  }
  int lane = threadIdx.x & 63, wid = threadIdx.x >> 6;
#pragma unroll
  for (int o = 32; o > 0; o >>= 1) ss += __shfl_down(ss, o, 64);
  __shared__ float sh[4];
  if (lane == 0) sh[wid] = ss;
  __syncthreads();
  if (threadIdx.x == 0) {
    float tot = sh[0] + sh[1] + sh[2] + sh[3];
    invY[j] = 1.f / fmaxf(sqrtf(tot), 1e-8f);
  }
}

// ------------------------------------------- Z norms + sim at label (fallback path)
__global__ __launch_bounds__(256) void k_zrow(
    const float* __restrict__ Z, const float* __restrict__ Y,
    const int* __restrict__ labels, const float* __restrict__ invY,
    float* __restrict__ invZ, float* __restrict__ simL, int f) {
  int i = blockIdx.x;
  int lab = labels[i];
  const float* zr = Z + (size_t)i * f;
  const float* yr = Y + (size_t)lab * f;
  float ss = 0.f, dt = 0.f;
  for (int k = threadIdx.x * 4; k < f; k += 256 * 4) {
    float4 z = *(const float4*)(zr + k);
    float4 y = *(const float4*)(yr + k);
    ss += z.x * z.x + z.y * z.y + z.z * z.z + z.w * z.w;
    dt += z.x * y.x + z.y * y.y + z.z * y.z + z.w * y.w;
  }
  int lane = threadIdx.x & 63, wid = threadIdx.x >> 6;
#pragma unroll
  for (int o = 32; o > 0; o >>= 1) {
    ss += __shfl_down(ss, o, 64);
    dt += __shfl_down(dt, o, 64);
  }
  __shared__ float shs[4], shd[4];
  if (lane == 0) { shs[wid] = ss; shd[wid] = dt; }
  __syncthreads();
  if (threadIdx.x == 0) {
    float S = shs[0] + shs[1] + shs[2] + shs[3];
    float D = shd[0] + shd[1] + shd[2] + shd[3];
    float iz = 1.f / fmaxf(sqrtf(S), 1e-8f);
    invZ[i] = iz;
    simL[i] = D * iz * invY[lab];
  }
}

// ------------------------------------------------- split helpers
__device__ __forceinline__ uint rne_hi_bits(uint u) {
  return (u + 0x7fffu + ((u >> 16) & 1u)) & 0xffff0000u;
}

__device__ __forceinline__ void split_pack8(float4 a, float4 b, uint4& hi, uint4& lo) {
  float v[8] = {a.x, a.y, a.z, a.w, b.x, b.y, b.z, b.w};
  uint h[8], l[8];
#pragma unroll
  for (int i = 0; i < 8; ++i) {
    uint u = __float_as_uint(v[i]);
    uint rh = rne_hi_bits(u);
    h[i] = rh;
    float d = v[i] - __uint_as_float(rh);  // exact (Sterbenz)
    uint ud = __float_as_uint(d);
    l[i] = (ud + 0x7fffu + ((ud >> 16) & 1u));
  }
  hi = make_uint4((h[0] >> 16) | h[1], (h[2] >> 16) | h[3],
                  (h[4] >> 16) | h[5], (h[6] >> 16) | h[7]);
  lo = make_uint4((l[0] >> 16) | (l[1] & 0xffff0000u),
                  (l[2] >> 16) | (l[3] & 0xffff0000u),
                  (l[4] >> 16) | (l[5] & 0xffff0000u),
                  (l[6] >> 16) | (l[7] & 0xffff0000u));
}

// --------------------------------------------- panel pack kernels
// Z panel (per 128-row tile rt, per 32-k chunk kc): 16 KB = [Ah 8KB][Al 8KB],
// row rl stride 64 B, data chunk kq stored at chunk (kq ^ ((rl>>1)&3)).
// Y panel (160-row tiles): 20 KB = [Bh 10KB][Bl 10KB], same swizzle.
// k_packZ also fuses the zrow computation (invZ, simL) — one wave per row.
__global__ __launch_bounds__(256) void k_packZ(const float* __restrict__ Z,
                                               const float* __restrict__ Y,
                                               const int* __restrict__ labels,
                                               const float* __restrict__ invY,
                                               char* __restrict__ Zpan,
                                               float* __restrict__ invZ,
                                               float* __restrict__ simL,
                                               int f, int nkc) {
  int r = blockIdx.x * 4 + (threadIdx.x >> 6);
  int lane = threadIdx.x & 63;
  int rt = r >> 7, rl = r & 127;
  char* pan = Zpan + (size_t)rt * nkc * 16384;
  const float* row = Z + (size_t)r * f;
  int lab = labels[r];
  const float* yrow = Y + (size_t)lab * f;
  float ss = 0.f, dt = 0.f;
  int niter = f >> 9;  // f/8 chunks / 64 lanes
  for (int j = 0; j < niter; ++j) {
    int gq = lane + 64 * j;
    float4 v0 = *(const float4*)(row + gq * 8);
    float4 v1 = *(const float4*)(row + gq * 8 + 4);
    float4 y0 = *(const float4*)(yrow + gq * 8);
    float4 y1 = *(const float4*)(yrow + gq * 8 + 4);
    ss += v0.x * v0.x + v0.y * v0.y + v0.z * v0.z + v0.w * v0.w +
          v1.x * v1.x + v1.y * v1.y + v1.z * v1.z + v1.w * v1.w;
    dt += v0.x * y0.x + v0.y * y0.y + v0.z * y0.z + v0.w * y0.w +
          v1.x * y1.x + v1.y * y1.y + v1.z * y1.z + v1.w * y1.w;
    uint4 h, l;
    split_pack8(v0, v1, h, l);
    int kc = gq >> 2, kq = gq & 3;
    size_t off = (size_t)kc * 16384 + rl * 64 + ((kq ^ ((rl >> 1) & 3)) << 4);
    *(uint4*)(pan + off) = h;
    *(uint4*)(pan + off + 8192) = l;
  }
#pragma unroll
  for (int o = 32; o > 0; o >>= 1) {
    ss += __shfl_down(ss, o, 64);
    dt += __shfl_down(dt, o, 64);
  }
  if (lane == 0) {
    float iz = 1.f / fmaxf(sqrtf(ss), 1e-8f);
    invZ[r] = iz;
    simL[r] = dt * iz * invY[lab];
  }
}

__global__ __launch_bounds__(256) void k_packY(const float* __restrict__ Y,
                                               char* __restrict__ Ypan,
                                               float* __restrict__ invY,
                                               int s, int f, int nkc) {
  int r = blockIdx.x * 4 + (threadIdx.x >> 6);
  int lane = threadIdx.x & 63;
  int ct = r / 160, rl = r % 160;
  char* pan = Ypan + (size_t)ct * nkc * 20480;
  const float* row = Y + (size_t)r * f;
  const bool ok = r < s;
  float ss = 0.f;
  int niter = f >> 9;
  for (int j = 0; j < niter; ++j) {
    int gq = lane + 64 * j;
    float4 v0 = {}, v1 = {};
    if (ok) {
      v0 = *(const float4*)(row + gq * 8);
      v1 = *(const float4*)(row + gq * 8 + 4);
    }
    ss += v0.x * v0.x + v0.y * v0.y + v0.z * v0.z + v0.w * v0.w +
          v1.x * v1.x + v1.y * v1.y + v1.z * v1.z + v1.w * v1.w;
    uint4 h, l;
    split_pack8(v0, v1, h, l);
    int kc = gq >> 2, kq = gq & 3;
    size_t off = (size_t)kc * 20480 + rl * 64 + ((kq ^ ((rl >> 1) & 3)) << 4);
    *(uint4*)(pan + off) = h;
    *(uint4*)(pan + off + 10240) = l;
  }
  if (ok) {
#pragma unroll
    for (int o = 32; o > 0; o >>= 1) ss += __shfl_down(ss, o, 64);
    if (lane == 0) invY[r] = 1.f / fmaxf(sqrtf(ss), 1e-8f);
  }
}

// ------------------------------------------------- DMA helper
__device__ __forceinline__ void dma16(const void* g, void* l) {
  __builtin_amdgcn_global_load_lds((const __attribute__((address_space(1))) unsigned int*)g,
                                   (__attribute__((address_space(3))) unsigned int*)l,
                                   16, 0, 0);
}

// ------------------------------------------------- main GEMM (panel path)
// TM=128, TN=160, BK=32. 4 waves in 2x2, each owns 64x80 (4x5 tiles).
// Ping-pong LDS: two 36 KB images [Ah 8K][Al 8K][Bh 10K][Bl 10K].
// K-loop: barrier -> issue next-image DMA -> compute current image.
// The vmcnt(0) drain at each barrier then waits on DMAs issued a full
// compute-phase (~1400 cyc) earlier -> latency hidden.
#define IMG 36864

__global__ __launch_bounds__(256, 2) void k_gemm_rank_pan(
    const char* __restrict__ Zpan, const char* __restrict__ Ypan,
    const float* __restrict__ invZ, const float* __restrict__ invY,
    const float* __restrict__ simL, const int* __restrict__ labels,
    int* __restrict__ rank, int b, int s, int nkc) {
  __shared__ ushort SMu[IMG];  // 2 images x 36864 B
  char* SMb = (char*)SMu;
  __shared__ float sL[128], sIz[128];
  __shared__ int sLab[128], sCnt[128];

  const int t = threadIdx.x;
  const int row0 = blockIdx.x * 128;   // x = row tile (fast-varying for L3 reuse)
  const int col0 = blockIdx.y * 160;

  if (t < 128) {
    int gi = row0 + t;
    sL[t] = simL[gi]; sIz[t] = invZ[gi]; sLab[t] = labels[gi];
    sCnt[t] = 0;
  }

  const char* srcA = Zpan + (size_t)blockIdx.x * nkc * 16384 + t * 16;
  const char* srcB = Ypan + (size_t)blockIdx.y * nkc * 20480 + t * 16;

  const int lane = t & 63;
  const int wv = t >> 6;
  const int wr = wv >> 1, wc = wv & 1;   // wave: rows wr*64, cols wc*80
  const int fm = lane & 15, quad = lane >> 4;

  int aoff[4], boff[5];
#pragma unroll
  for (int i = 0; i < 4; ++i) {
    int r = wr * 64 + i * 16 + fm;
    aoff[i] = r * 64 + ((quad ^ ((r >> 1) & 3)) << 4);
  }
#pragma unroll
  for (int i = 0; i < 5; ++i) {
    int c = wc * 80 + i * 16 + fm;
    boff[i] = 16384 + c * 64 + ((quad ^ ((c >> 1) & 3)) << 4);
  }

  f32x4 acc[4][5] = {};

  // prologue: DMA image 0
#pragma unroll
  for (int j = 0; j < 4; ++j) dma16(srcA + j * 4096, SMb + j * 4096 + t * 16);
#pragma unroll
  for (int j = 0; j < 5; ++j) dma16(srcB + j * 4096, SMb + 16384 + j * 4096 + t * 16);
  srcA += 16384; srcB += 20480;

  for (int kt = 0; kt < nkc; ++kt) {
    char* cur = SMb + (kt & 1) * IMG;
    char* nxt = SMb + ((kt + 1) & 1) * IMG;
    __syncthreads();  // drains cur's DMAs (in flight during prev compute) +
                      // guarantees prev reads of nxt are done
    if (kt + 1 < nkc) {
#pragma unroll
      for (int j = 0; j < 4; ++j) dma16(srcA + j * 4096, nxt + j * 4096 + t * 16);
#pragma unroll
      for (int j = 0; j < 5; ++j) dma16(srcB + j * 4096, nxt + 16384 + j * 4096 + t * 16);
      srcA += 16384; srcB += 20480;
    }

    s16x8 ah[4], al[4];
#pragma unroll
    for (int i = 0; i < 4; ++i) {
      ah[i] = *(const s16x8*)(cur + aoff[i]);
      al[i] = *(const s16x8*)(cur + aoff[i] + 8192);
    }
#pragma unroll
    for (int cc = 0; cc < 5; ++cc) {
      s16x8 bh = *(const s16x8*)(cur + boff[cc]);
      s16x8 bl = *(const s16x8*)(cur + boff[cc] + 10240);
#pragma unroll
      for (int rr = 0; rr < 4; ++rr) {
        acc[rr][cc] = __builtin_amdgcn_mfma_f32_16x16x32_bf16(ah[rr], bh, acc[rr][cc], 0, 0, 0);
        acc[rr][cc] = __builtin_amdgcn_mfma_f32_16x16x32_bf16(ah[rr], bl, acc[rr][cc], 0, 0, 0);
        acc[rr][cc] = __builtin_amdgcn_mfma_f32_16x16x32_bf16(al[rr], bh, acc[rr][cc], 0, 0, 0);
      }
    }
  }

  // ---- epilogue (C/D layout: col=lane&15, row=quad*4+reg)
  float iYc[5];
#pragma unroll
  for (int c = 0; c < 5; ++c) {
    int gj = col0 + wc * 80 + c * 16 + fm;
    iYc[c] = (gj < s) ? invY[gj] : 0.f;
  }

#pragma unroll
  for (int rr = 0; rr < 4; ++rr) {
#pragma unroll
    for (int reg = 0; reg < 4; ++reg) {
      int li = wr * 64 + rr * 16 + quad * 4 + reg;
      float iz = sIz[li], sl = sL[li];
      int lab = sLab[li];
      int cnt = 0;
#pragma unroll
      for (int c = 0; c < 5; ++c) {
        int gj = col0 + wc * 80 + c * 16 + fm;
        if (gj < s && gj != lab) {
          float sim = acc[rr][c][reg] * iz * iYc[c];
          cnt += (sim > sl || (sim == sl && gj < lab)) ? 1 : 0;
        }
      }
      cnt += __shfl_down(cnt, 8, 16);
      cnt += __shfl_down(cnt, 4, 16);
      cnt += __shfl_down(cnt, 2, 16);
      cnt += __shfl_down(cnt, 1, 16);
      if (fm == 0 && cnt) atomicAdd(&sCnt[li], cnt);
    }
  }
  __syncthreads();
  if (t < 128) {
    int gi = row0 + t;
    if (sCnt[t]) atomicAdd(&rank[gi], sCnt[t]);
  }
}

// ------------------------------------------------- fallback GEMM (R2-proven)
#define TMF 128
#define TNF 128
#define BKF 32
#define SKF 40

__global__ __launch_bounds__(256) void k_gemm_rank_v2(
    const float* __restrict__ Z, const float* __restrict__ Y,
    const float* __restrict__ invZ, const float* __restrict__ invY,
    const float* __restrict__ simL, const int* __restrict__ labels,
    int* __restrict__ rank, int b, int s, int f) {
  __shared__ short Ah[TMF * SKF], Al[TMF * SKF], Bh[TNF * SKF], Bl[TNF * SKF];
  __shared__ float sL[TMF], sIz[TMF];
  __shared__ int sLab[TMF], sCnt[TMF];

  const int t = threadIdx.x;
  const int row0 = blockIdx.y * TMF;
  const int col0 = blockIdx.x * TNF;

  if (t < TMF) {
    int gi = row0 + t;
    if (gi < b) { sL[t] = simL[gi]; sIz[t] = invZ[gi]; sLab[t] = labels[gi]; }
    else        { sL[t] = 0.f;      sIz[t] = 0.f;      sLab[t] = -1; }
    sCnt[t] = 0;
  }

  const int srow  = t >> 1;
  const int skoff = (t & 1) << 4;
  const bool zok = (row0 + srow) < b;
  const bool yok = (col0 + srow) < s;
  const float* zp = Z + (size_t)(row0 + srow) * f + skoff;
  const float* yp = Y + (size_t)(col0 + srow) * f + skoff;

  const int lane = t & 63;
  const int wv = t >> 6;
  const int wr = wv >> 1, wc = wv & 1;
  const int fm = lane & 15, quad = lane >> 4;

  f32x4 acc[4][4] = {};

  for (int kt = 0; kt < f; kt += BKF) {
    float4 z0 = {}, z1 = {}, z2 = {}, z3 = {};
    float4 y0 = {}, y1 = {}, y2 = {}, y3 = {};
    if (zok) {
      z0 = *(const float4*)(zp + 0); z1 = *(const float4*)(zp + 4);
      z2 = *(const float4*)(zp + 8); z3 = *(const float4*)(zp + 12);
    }
    if (yok) {
      y0 = *(const float4*)(yp + 0); y1 = *(const float4*)(yp + 4);
      y2 = *(const float4*)(yp + 8); y3 = *(const float4*)(yp + 12);
    }
    zp += BKF; yp += BKF;

    __syncthreads();

    uint4 h, l;
    split_pack8(z0, z1, h, l);
    *(uint4*)(Ah + srow * SKF + skoff)     = h;
    *(uint4*)(Al + srow * SKF + skoff)     = l;
    split_pack8(z2, z3, h, l);
    *(uint4*)(Ah + srow * SKF + skoff + 8) = h;
    *(uint4*)(Al + srow * SKF + skoff + 8) = l;
    split_pack8(y0, y1, h, l);
    *(uint4*)(Bh + srow * SKF + skoff)     = h;
    *(uint4*)(Bl + srow * SKF + skoff)     = l;
    split_pack8(y2, y3, h, l);
    *(uint4*)(Bh + srow * SKF + skoff + 8) = h;
    *(uint4*)(Bl + srow * SKF + skoff + 8) = l;

    __syncthreads();

    s16x8 ah[4], al4[4], bh[4], bl4[4];
#pragma unroll
    for (int rr = 0; rr < 4; ++rr) {
      int ar = wr * 64 + rr * 16 + fm;
      ah[rr]  = *(const s16x8*)(Ah + ar * SKF + quad * 8);
      al4[rr] = *(const s16x8*)(Al + ar * SKF + quad * 8);
    }
#pragma unroll
    for (int cc = 0; cc < 4; ++cc) {
      int br = wc * 64 + cc * 16 + fm;
      bh[cc]  = *(const s16x8*)(Bh + br * SKF + quad * 8);
      bl4[cc] = *(const s16x8*)(Bl + br * SKF + quad * 8);
    }
#pragma unroll
    for (int rr = 0; rr < 4; ++rr)
#pragma unroll
      for (int cc = 0; cc < 4; ++cc) {
        acc[rr][cc] = __builtin_amdgcn_mfma_f32_16x16x32_bf16(ah[rr],  bh[cc],  acc[rr][cc], 0, 0, 0);
        acc[rr][cc] = __builtin_amdgcn_mfma_f32_16x16x32_bf16(ah[rr],  bl4[cc], acc[rr][cc], 0, 0, 0);
        acc[rr][cc] = __builtin_amdgcn_mfma_f32_16x16x32_bf16(al4[rr], bh[cc],  acc[rr][cc], 0, 0, 0);
      }
  }

  float iYc[4]; int gjc[4];
#pragma unroll
  for (int c = 0; c < 4; ++c) {
    int gj = col0 + wc * 64 + c * 16 + fm;
    gjc[c] = gj;
    iYc[c] = (gj < s) ? invY[gj] : 0.f;
  }

#pragma unroll
  for (int rr = 0; rr < 4; ++rr) {
#pragma unroll
    for (int reg = 0; reg < 4; ++reg) {
      int li = wr * 64 + rr * 16 + quad * 4 + reg;
      int gi = row0 + li;
      int cnt = 0;
      if (gi < b) {
        float iz = sIz[li], sl = sL[li];
        int lab = sLab[li];
#pragma unroll
        for (int c = 0; c < 4; ++c) {
          int gj = gjc[c];
          if (gj < s && gj != lab) {
            float sim = acc[rr][c][reg] * iz * iYc[c];
            cnt += (sim > sl || (sim == sl && gj < lab)) ? 1 : 0;
          }
        }
      }
      cnt += __shfl_down(cnt, 8, 16);
      cnt += __shfl_down(cnt, 4, 16);
      cnt += __shfl_down(cnt, 2, 16);
      cnt += __shfl_down(cnt, 1, 16);
      if (fm == 0 && cnt) atomicAdd(&sCnt[li], cnt);
    }
  }
  __syncthreads();
  if (t < TMF) {
    int gi = row0 + t;
    if (gi < b && sCnt[t]) atomicAdd(&rank[gi], sCnt[t]);
  }
}

// ---------------------------------------------------------------- finalize
__global__ __launch_bounds__(256) void k_final(const int* __restrict__ rank,
                                               float* __restrict__ out, int b) {
  int c1 = 0, c5 = 0;
  for (int i = threadIdx.x; i < b; i += 256) {
    int r = rank[i];
    c1 += (r < 1);
    c5 += (r < 5);
  }
  int lane = threadIdx.x & 63, wid = threadIdx.x >> 6;
#pragma unroll
  for (int o = 32; o > 0; o >>= 1) {
    c1 += __shfl_down(c1, o, 64);
    c5 += __shfl_down(c5, o, 64);
  }
  __shared__ int s1[4], s5[4];
  if (lane == 0) { s1[wid] = c1; s5[wid] = c5; }
  __syncthreads();
  if (threadIdx.x == 0) {
    int t1 = s1[0] + s1[1] + s1[2] + s1[3];
    int t5 = s5[0] + s5[1] + s5[2] + s5[3];
    out[0] = (float)t1 / (float)b;
    out[1] = (float)t5 / (float)b;
  }
}

// ---------------------------------------------------------------- launch
extern "C" void kernel_launch(void* const* d_in, const int* in_sizes, int n_in,
                              void* d_out, int out_size, void* d_ws, size_t ws_size,
                              hipStream_t stream) {
  const float* Z  = (const float*)d_in[0];
  const int* yi   = (const int*)d_in[1];
  const float* Y  = (const float*)d_in[2];
  const int* tyi  = (const int*)d_in[3];
  const int b = in_sizes[1];
  const int s = in_sizes[3];
  const int f = in_sizes[0] / b;
  float* out = (float*)d_out;

  char* p = (char*)d_ws;
  size_t used = 0;
  auto alloc = [&](size_t bytes) {
    char* r = p;
    size_t a = (bytes + 255) & ~(size_t)255;
    p += a; used += a;
    return r;
  };
  int* inv     = (int*)alloc((size_t)s * 4);
  int* labels  = (int*)alloc((size_t)b * 4);
  int* rank    = (int*)alloc((size_t)b * 4);
  float* invY  = (float*)alloc((size_t)s * 4);
  float* invZ  = (float*)alloc((size_t)b * 4);
  float* simL  = (float*)alloc((size_t)b * 4);

  const int nkc = f >> 5;                  // k-chunks of 32
  const int nrt = b / 128;                 // Z row tiles
  const int nct = (s + 159) / 160;         // Y col tiles (padded)
  const int rows_pad = nct * 160;
  const size_t zpan_sz = (size_t)nrt * nkc * 16384;
  const size_t ypan_sz = (size_t)nct * nkc * 20480;
  const size_t need = used + zpan_sz + ypan_sz + 1024;
  const bool use_pan = (ws_size >= need) && (b % 128 == 0) && (f % 512 == 0);

  hipMemsetAsync(rank, 0, (size_t)b * 4, stream);
  k_init_inv<<<(s + 255) / 256, 256, 0, stream>>>(inv, s);
  k_scatter<<<(s + 255) / 256, 256, 0, stream>>>(tyi, inv, s);
  k_labels<<<(b + 255) / 256, 256, 0, stream>>>(yi, inv, labels, b, s);

  if (use_pan) {
    char* Zpan = (char*)alloc(zpan_sz);
    char* Ypan = (char*)alloc(ypan_sz);
    k_packY<<<rows_pad / 4, 256, 0, stream>>>(Y, Ypan, invY, s, f, nkc);
    k_packZ<<<b / 4, 256, 0, stream>>>(Z, Y, labels, invY, Zpan, invZ, simL, f, nkc);
    dim3 grid(nrt, nct);  // x = row tile (fast) -> concurrent blocks share col tile
    k_gemm_rank_pan<<<grid, 256, 0, stream>>>(Zpan, Ypan, invZ, invY, simL,
                                              labels, rank, b, s, nkc);
  } else {
    k_ynorm<<<s, 256, 0, stream>>>(Y, invY, f);
    k_zrow<<<b, 256, 0, stream>>>(Z, Y, labels, invY, invZ, simL, f);
    dim3 grid((s + TNF - 1) / TNF, (b + TMF - 1) / TMF);
    k_gemm_rank_v2<<<grid, 256, 0, stream>>>(Z, Y, invZ, invY, simL, labels,
                                             rank, b, s, f);
  }
  k_final<<<1, 256, 0, stream>>>(rank, out, b);
}

// Round 7
// 765.398 us; speedup vs baseline: 1.1679x; 1.1679x over previous
//
#include <hip/hip_runtime.h>

#define INT_MAX_C 0x7fffffff

typedef __attribute__((ext_vector_type(8))) short s16x8;
typedef __attribute__((ext_vector_type(4))) float f32x4;

// ---------------------------------------------------------------- label prep
__global__ void k_init_inv(int* inv, int s) {
  int j = blockIdx.x * 256 + threadIdx.x;
  if (j < s) inv[j] = INT_MAX_C;
}

__global__ void k_scatter(const int* __restrict__ tyi, int* __restrict__ inv, int s) {
  int j = blockIdx.x * 256 + threadIdx.x;
  if (j < s) {
    int v = tyi[j];
    if (v >= 0 && v < s) atomicMin(&inv[v], j);
  }
}

__global__ void k_labels(const int* __restrict__ yi, const int* __restrict__ inv,
                         int* __restrict__ labels, int b, int s) {
  int i = blockIdx.x * 256 + threadIdx.x;
  if (i < b) {
    int v = yi[i];
    int lab = 0;
    if (v >= 0 && v < s) { int p = inv[v]; if (p != INT_MAX_C) lab = p; }
    labels[i] = lab;
  }
}

// ---------------------------------------------------------------- Y norms (fallback path)
__global__ __launch_bounds__(256) void k_ynorm(const float* __restrict__ Y,
                                               float* __restrict__ invY, int f) {
  int j = blockIdx.x;
  const float* row = Y + (size_t)j * f;
  float ss = 0.f;
  for (int k = threadIdx.x * 4; k < f; k += 256 * 4) {
    float4 v = *(const float4*)(row + k);
    ss += v.x * v.x + v.y * v.y + v.z * v.z + v.w * v.w;
  }
  int lane = threadIdx.x & 63, wid = threadIdx.x >> 6;
#pragma unroll
  for (int o = 32; o > 0; o >>= 1) ss += __shfl_down(ss, o, 64);
  __shared__ float sh[4];
  if (lane == 0) sh[wid] = ss;
  __syncthreads();
  if (threadIdx.x == 0) {
    float tot = sh[0] + sh[1] + sh[2] + sh[3];
    invY[j] = 1.f / fmaxf(sqrtf(tot), 1e-8f);
  }
}

// ------------------------------------------- Z norms + sim at label (fallback path)
__global__ __launch_bounds__(256) void k_zrow(
    const float* __restrict__ Z, const float* __restrict__ Y,
    const int* __restrict__ labels, const float* __restrict__ invY,
    float* __restrict__ invZ, float* __restrict__ simL, int f) {
  int i = blockIdx.x;
  int lab = labels[i];
  const float* zr = Z + (size_t)i * f;
  const float* yr = Y + (size_t)lab * f;
  float ss = 0.f, dt = 0.f;
  for (int k = threadIdx.x * 4; k < f; k += 256 * 4) {
    float4 z = *(const float4*)(zr + k);
    float4 y = *(const float4*)(yr + k);
    ss += z.x * z.x + z.y * z.y + z.z * z.z + z.w * z.w;
    dt += z.x * y.x + z.y * y.y + z.z * y.z + z.w * y.w;
  }
  int lane = threadIdx.x & 63, wid = threadIdx.x >> 6;
#pragma unroll
  for (int o = 32; o > 0; o >>= 1) {
    ss += __shfl_down(ss, o, 64);
    dt += __shfl_down(dt, o, 64);
  }
  __shared__ float shs[4], shd[4];
  if (lane == 0) { shs[wid] = ss; shd[wid] = dt; }
  __syncthreads();
  if (threadIdx.x == 0) {
    float S = shs[0] + shs[1] + shs[2] + shs[3];
    float D = shd[0] + shd[1] + shd[2] + shd[3];
    float iz = 1.f / fmaxf(sqrtf(S), 1e-8f);
    invZ[i] = iz;
    simL[i] = D * iz * invY[lab];
  }
}

// ------------------------------------------------- split helpers
__device__ __forceinline__ uint rne_hi_bits(uint u) {
  return (u + 0x7fffu + ((u >> 16) & 1u)) & 0xffff0000u;
}

__device__ __forceinline__ void split_pack8(float4 a, float4 b, uint4& hi, uint4& lo) {
  float v[8] = {a.x, a.y, a.z, a.w, b.x, b.y, b.z, b.w};
  uint h[8], l[8];
#pragma unroll
  for (int i = 0; i < 8; ++i) {
    uint u = __float_as_uint(v[i]);
    uint rh = rne_hi_bits(u);
    h[i] = rh;
    float d = v[i] - __uint_as_float(rh);  // exact (Sterbenz)
    uint ud = __float_as_uint(d);
    l[i] = (ud + 0x7fffu + ((ud >> 16) & 1u));
  }
  hi = make_uint4((h[0] >> 16) | h[1], (h[2] >> 16) | h[3],
                  (h[4] >> 16) | h[5], (h[6] >> 16) | h[7]);
  lo = make_uint4((l[0] >> 16) | (l[1] & 0xffff0000u),
                  (l[2] >> 16) | (l[3] & 0xffff0000u),
                  (l[4] >> 16) | (l[5] & 0xffff0000u),
                  (l[6] >> 16) | (l[7] & 0xffff0000u));
}

// --------------------------------------------- panel pack kernels
// Z panel (per 128-row tile rt, per 32-k chunk kc): 16 KB = [Ah 8KB][Al 8KB],
// row rl stride 64 B, data chunk kq stored at chunk (kq ^ ((rl>>1)&3)).
// Y panel (160-row tiles): 20 KB = [Bh 10KB][Bl 10KB], same swizzle.
// k_packZ also fuses the zrow computation (invZ, simL) — one wave per row.
__global__ __launch_bounds__(256) void k_packZ(const float* __restrict__ Z,
                                               const float* __restrict__ Y,
                                               const int* __restrict__ labels,
                                               const float* __restrict__ invY,
                                               char* __restrict__ Zpan,
                                               float* __restrict__ invZ,
                                               float* __restrict__ simL,
                                               int f, int nkc) {
  int r = blockIdx.x * 4 + (threadIdx.x >> 6);
  int lane = threadIdx.x & 63;
  int rt = r >> 7, rl = r & 127;
  char* pan = Zpan + (size_t)rt * nkc * 16384;
  const float* row = Z + (size_t)r * f;
  int lab = labels[r];
  const float* yrow = Y + (size_t)lab * f;
  float ss = 0.f, dt = 0.f;
  int niter = f >> 9;  // f/8 chunks / 64 lanes
  for (int j = 0; j < niter; ++j) {
    int gq = lane + 64 * j;
    float4 v0 = *(const float4*)(row + gq * 8);
    float4 v1 = *(const float4*)(row + gq * 8 + 4);
    float4 y0 = *(const float4*)(yrow + gq * 8);
    float4 y1 = *(const float4*)(yrow + gq * 8 + 4);
    ss += v0.x * v0.x + v0.y * v0.y + v0.z * v0.z + v0.w * v0.w +
          v1.x * v1.x + v1.y * v1.y + v1.z * v1.z + v1.w * v1.w;
    dt += v0.x * y0.x + v0.y * y0.y + v0.z * y0.z + v0.w * y0.w +
          v1.x * y1.x + v1.y * y1.y + v1.z * y1.z + v1.w * y1.w;
    uint4 h, l;
    split_pack8(v0, v1, h, l);
    int kc = gq >> 2, kq = gq & 3;
    size_t off = (size_t)kc * 16384 + rl * 64 + ((kq ^ ((rl >> 1) & 3)) << 4);
    *(uint4*)(pan + off) = h;
    *(uint4*)(pan + off + 8192) = l;
  }
#pragma unroll
  for (int o = 32; o > 0; o >>= 1) {
    ss += __shfl_down(ss, o, 64);
    dt += __shfl_down(dt, o, 64);
  }
  if (lane == 0) {
    float iz = 1.f / fmaxf(sqrtf(ss), 1e-8f);
    invZ[r] = iz;
    simL[r] = dt * iz * invY[lab];
  }
}

__global__ __launch_bounds__(256) void k_packY(const float* __restrict__ Y,
                                               char* __restrict__ Ypan,
                                               float* __restrict__ invY,
                                               int s, int f, int nkc) {
  int r = blockIdx.x * 4 + (threadIdx.x >> 6);
  int lane = threadIdx.x & 63;
  int ct = r / 160, rl = r % 160;
  char* pan = Ypan + (size_t)ct * nkc * 20480;
  const float* row = Y + (size_t)r * f;
  const bool ok = r < s;
  float ss = 0.f;
  int niter = f >> 9;
  for (int j = 0; j < niter; ++j) {
    int gq = lane + 64 * j;
    float4 v0 = {}, v1 = {};
    if (ok) {
      v0 = *(const float4*)(row + gq * 8);
      v1 = *(const float4*)(row + gq * 8 + 4);
    }
    ss += v0.x * v0.x + v0.y * v0.y + v0.z * v0.z + v0.w * v0.w +
          v1.x * v1.x + v1.y * v1.y + v1.z * v1.z + v1.w * v1.w;
    uint4 h, l;
    split_pack8(v0, v1, h, l);
    int kc = gq >> 2, kq = gq & 3;
    size_t off = (size_t)kc * 20480 + rl * 64 + ((kq ^ ((rl >> 1) & 3)) << 4);
    *(uint4*)(pan + off) = h;
    *(uint4*)(pan + off + 10240) = l;
  }
  if (ok) {
#pragma unroll
    for (int o = 32; o > 0; o >>= 1) ss += __shfl_down(ss, o, 64);
    if (lane == 0) invY[r] = 1.f / fmaxf(sqrtf(ss), 1e-8f);
  }
}

// ------------------------------------------------- DMA helper
__device__ __forceinline__ void dma16(const void* g, void* l) {
  __builtin_amdgcn_global_load_lds((const __attribute__((address_space(1))) unsigned int*)g,
                                   (__attribute__((address_space(3))) unsigned int*)l,
                                   16, 0, 0);
}

// ------------------------------------------------- main GEMM (panel path)
// TM=128, TN=160, BK=32. 4 waves in 2x2, each owns 64x80 (4x5 tiles).
// SINGLE buffer (R6 post-mortem: dbuf burned LDS->2 blocks/CU and lost).
// acc = 80 AGPR + ~88 arch VGPR = 168 <= 170 -> 3 waves/SIMD with
// __launch_bounds__(256,3); LDS 38 KB -> not the limiter. 3 blocks/CU.
__global__ __launch_bounds__(256, 3) void k_gemm_rank_pan(
    const char* __restrict__ Zpan, const char* __restrict__ Ypan,
    const float* __restrict__ invZ, const float* __restrict__ invY,
    const float* __restrict__ simL, const int* __restrict__ labels,
    int* __restrict__ rank, int b, int s, int nkc) {
  __shared__ ushort SMu[18432];  // 36864 B: [Ah 8K][Al 8K][Bh 10K][Bl 10K]
  char* SMb = (char*)SMu;
  __shared__ float sL[128], sIz[128];
  __shared__ int sLab[128], sCnt[128];

  const int t = threadIdx.x;
  const int row0 = blockIdx.x * 128;   // x = row tile (fast-varying for L3 reuse)
  const int col0 = blockIdx.y * 160;

  if (t < 128) {
    int gi = row0 + t;
    sL[t] = simL[gi]; sIz[t] = invZ[gi]; sLab[t] = labels[gi];
    sCnt[t] = 0;
  }

  const char* srcA = Zpan + (size_t)blockIdx.x * nkc * 16384 + t * 16;
  const char* srcB = Ypan + (size_t)blockIdx.y * nkc * 20480 + t * 16;

  const int lane = t & 63;
  const int wv = t >> 6;
  const int wr = wv >> 1, wc = wv & 1;   // wave: rows wr*64, cols wc*80
  const int fm = lane & 15, quad = lane >> 4;

  int aoff[4], boff[5];
#pragma unroll
  for (int i = 0; i < 4; ++i) {
    int r = wr * 64 + i * 16 + fm;
    aoff[i] = r * 64 + ((quad ^ ((r >> 1) & 3)) << 4);
  }
#pragma unroll
  for (int i = 0; i < 5; ++i) {
    int c = wc * 80 + i * 16 + fm;
    boff[i] = 16384 + c * 64 + ((quad ^ ((c >> 1) & 3)) << 4);
  }

  f32x4 acc[4][5] = {};

  for (int kt = 0; kt < nkc; ++kt) {
    __syncthreads();  // prior-iter fragment reads complete
#pragma unroll
    for (int j = 0; j < 4; ++j) dma16(srcA + j * 4096, SMb + j * 4096 + t * 16);
#pragma unroll
    for (int j = 0; j < 5; ++j) dma16(srcB + j * 4096, SMb + 16384 + j * 4096 + t * 16);
    srcA += 16384; srcB += 20480;
    __syncthreads();  // DMA drained

    s16x8 ah[4], al[4];
#pragma unroll
    for (int i = 0; i < 4; ++i) {
      ah[i] = *(const s16x8*)(SMb + aoff[i]);
      al[i] = *(const s16x8*)(SMb + aoff[i] + 8192);
    }
#pragma unroll
    for (int cc = 0; cc < 5; ++cc) {
      s16x8 bh = *(const s16x8*)(SMb + boff[cc]);
      s16x8 bl = *(const s16x8*)(SMb + boff[cc] + 10240);
#pragma unroll
      for (int rr = 0; rr < 4; ++rr) {
        acc[rr][cc] = __builtin_amdgcn_mfma_f32_16x16x32_bf16(ah[rr], bh, acc[rr][cc], 0, 0, 0);
        acc[rr][cc] = __builtin_amdgcn_mfma_f32_16x16x32_bf16(ah[rr], bl, acc[rr][cc], 0, 0, 0);
        acc[rr][cc] = __builtin_amdgcn_mfma_f32_16x16x32_bf16(al[rr], bh, acc[rr][cc], 0, 0, 0);
      }
    }
  }

  // ---- epilogue (C/D layout: col=lane&15, row=quad*4+reg)
  float iYc[5];
#pragma unroll
  for (int c = 0; c < 5; ++c) {
    int gj = col0 + wc * 80 + c * 16 + fm;
    iYc[c] = (gj < s) ? invY[gj] : 0.f;
  }

#pragma unroll
  for (int rr = 0; rr < 4; ++rr) {
#pragma unroll
    for (int reg = 0; reg < 4; ++reg) {
      int li = wr * 64 + rr * 16 + quad * 4 + reg;
      float iz = sIz[li], sl = sL[li];
      int lab = sLab[li];
      int cnt = 0;
#pragma unroll
      for (int c = 0; c < 5; ++c) {
        int gj = col0 + wc * 80 + c * 16 + fm;
        if (gj < s && gj != lab) {
          float sim = acc[rr][c][reg] * iz * iYc[c];
          cnt += (sim > sl || (sim == sl && gj < lab)) ? 1 : 0;
        }
      }
      cnt += __shfl_down(cnt, 8, 16);
      cnt += __shfl_down(cnt, 4, 16);
      cnt += __shfl_down(cnt, 2, 16);
      cnt += __shfl_down(cnt, 1, 16);
      if (fm == 0 && cnt) atomicAdd(&sCnt[li], cnt);
    }
  }
  __syncthreads();
  if (t < 128) {
    int gi = row0 + t;
    if (sCnt[t]) atomicAdd(&rank[gi], sCnt[t]);
  }
}

// ------------------------------------------------- fallback GEMM (R2-proven)
#define TMF 128
#define TNF 128
#define BKF 32
#define SKF 40

__global__ __launch_bounds__(256) void k_gemm_rank_v2(
    const float* __restrict__ Z, const float* __restrict__ Y,
    const float* __restrict__ invZ, const float* __restrict__ invY,
    const float* __restrict__ simL, const int* __restrict__ labels,
    int* __restrict__ rank, int b, int s, int f) {
  __shared__ short Ah[TMF * SKF], Al[TMF * SKF], Bh[TNF * SKF], Bl[TNF * SKF];
  __shared__ float sL[TMF], sIz[TMF];
  __shared__ int sLab[TMF], sCnt[TMF];

  const int t = threadIdx.x;
  const int row0 = blockIdx.y * TMF;
  const int col0 = blockIdx.x * TNF;

  if (t < TMF) {
    int gi = row0 + t;
    if (gi < b) { sL[t] = simL[gi]; sIz[t] = invZ[gi]; sLab[t] = labels[gi]; }
    else        { sL[t] = 0.f;      sIz[t] = 0.f;      sLab[t] = -1; }
    sCnt[t] = 0;
  }

  const int srow  = t >> 1;
  const int skoff = (t & 1) << 4;
  const bool zok = (row0 + srow) < b;
  const bool yok = (col0 + srow) < s;
  const float* zp = Z + (size_t)(row0 + srow) * f + skoff;
  const float* yp = Y + (size_t)(col0 + srow) * f + skoff;

  const int lane = t & 63;
  const int wv = t >> 6;
  const int wr = wv >> 1, wc = wv & 1;
  const int fm = lane & 15, quad = lane >> 4;

  f32x4 acc[4][4] = {};

  for (int kt = 0; kt < f; kt += BKF) {
    float4 z0 = {}, z1 = {}, z2 = {}, z3 = {};
    float4 y0 = {}, y1 = {}, y2 = {}, y3 = {};
    if (zok) {
      z0 = *(const float4*)(zp + 0); z1 = *(const float4*)(zp + 4);
      z2 = *(const float4*)(zp + 8); z3 = *(const float4*)(zp + 12);
    }
    if (yok) {
      y0 = *(const float4*)(yp + 0); y1 = *(const float4*)(yp + 4);
      y2 = *(const float4*)(yp + 8); y3 = *(const float4*)(yp + 12);
    }
    zp += BKF; yp += BKF;

    __syncthreads();

    uint4 h, l;
    split_pack8(z0, z1, h, l);
    *(uint4*)(Ah + srow * SKF + skoff)     = h;
    *(uint4*)(Al + srow * SKF + skoff)     = l;
    split_pack8(z2, z3, h, l);
    *(uint4*)(Ah + srow * SKF + skoff + 8) = h;
    *(uint4*)(Al + srow * SKF + skoff + 8) = l;
    split_pack8(y0, y1, h, l);
    *(uint4*)(Bh + srow * SKF + skoff)     = h;
    *(uint4*)(Bl + srow * SKF + skoff)     = l;
    split_pack8(y2, y3, h, l);
    *(uint4*)(Bh + srow * SKF + skoff + 8) = h;
    *(uint4*)(Bl + srow * SKF + skoff + 8) = l;

    __syncthreads();

    s16x8 ah[4], al4[4], bh[4], bl4[4];
#pragma unroll
    for (int rr = 0; rr < 4; ++rr) {
      int ar = wr * 64 + rr * 16 + fm;
      ah[rr]  = *(const s16x8*)(Ah + ar * SKF + quad * 8);
      al4[rr] = *(const s16x8*)(Al + ar * SKF + quad * 8);
    }
#pragma unroll
    for (int cc = 0; cc < 4; ++cc) {
      int br = wc * 64 + cc * 16 + fm;
      bh[cc]  = *(const s16x8*)(Bh + br * SKF + quad * 8);
      bl4[cc] = *(const s16x8*)(Bl + br * SKF + quad * 8);
    }
#pragma unroll
    for (int rr = 0; rr < 4; ++rr)
#pragma unroll
      for (int cc = 0; cc < 4; ++cc) {
        acc[rr][cc] = __builtin_amdgcn_mfma_f32_16x16x32_bf16(ah[rr],  bh[cc],  acc[rr][cc], 0, 0, 0);
        acc[rr][cc] = __builtin_amdgcn_mfma_f32_16x16x32_bf16(ah[rr],  bl4[cc], acc[rr][cc], 0, 0, 0);
        acc[rr][cc] = __builtin_amdgcn_mfma_f32_16x16x32_bf16(al4[rr], bh[cc],  acc[rr][cc], 0, 0, 0);
      }
  }

  float iYc[4]; int gjc[4];
#pragma unroll
  for (int c = 0; c < 4; ++c) {
    int gj = col0 + wc * 64 + c * 16 + fm;
    gjc[c] = gj;
    iYc[c] = (gj < s) ? invY[gj] : 0.f;
  }

#pragma unroll
  for (int rr = 0; rr < 4; ++rr) {
#pragma unroll
    for (int reg = 0; reg < 4; ++reg) {
      int li = wr * 64 + rr * 16 + quad * 4 + reg;
      int gi = row0 + li;
      int cnt = 0;
      if (gi < b) {
        float iz = sIz[li], sl = sL[li];
        int lab = sLab[li];
#pragma unroll
        for (int c = 0; c < 4; ++c) {
          int gj = gjc[c];
          if (gj < s && gj != lab) {
            float sim = acc[rr][c][reg] * iz * iYc[c];
            cnt += (sim > sl || (sim == sl && gj < lab)) ? 1 : 0;
          }
        }
      }
      cnt += __shfl_down(cnt, 8, 16);
      cnt += __shfl_down(cnt, 4, 16);
      cnt += __shfl_down(cnt, 2, 16);
      cnt += __shfl_down(cnt, 1, 16);
      if (fm == 0 && cnt) atomicAdd(&sCnt[li], cnt);
    }
  }
  __syncthreads();
  if (t < TMF) {
    int gi = row0 + t;
    if (gi < b && sCnt[t]) atomicAdd(&rank[gi], sCnt[t]);
  }
}

// ---------------------------------------------------------------- finalize
__global__ __launch_bounds__(256) void k_final(const int* __restrict__ rank,
                                               float* __restrict__ out, int b) {
  int c1 = 0, c5 = 0;
  for (int i = threadIdx.x; i < b; i += 256) {
    int r = rank[i];
    c1 += (r < 1);
    c5 += (r < 5);
  }
  int lane = threadIdx.x & 63, wid = threadIdx.x >> 6;
#pragma unroll
  for (int o = 32; o > 0; o >>= 1) {
    c1 += __shfl_down(c1, o, 64);
    c5 += __shfl_down(c5, o, 64);
  }
  __shared__ int s1[4], s5[4];
  if (lane == 0) { s1[wid] = c1; s5[wid] = c5; }
  __syncthreads();
  if (threadIdx.x == 0) {
    int t1 = s1[0] + s1[1] + s1[2] + s1[3];
    int t5 = s5[0] + s5[1] + s5[2] + s5[3];
    out[0] = (float)t1 / (float)b;
    out[1] = (float)t5 / (float)b;
  }
}

// ---------------------------------------------------------------- launch
extern "C" void kernel_launch(void* const* d_in, const int* in_sizes, int n_in,
                              void* d_out, int out_size, void* d_ws, size_t ws_size,
                              hipStream_t stream) {
  const float* Z  = (const float*)d_in[0];
  const int* yi   = (const int*)d_in[1];
  const float* Y  = (const float*)d_in[2];
  const int* tyi  = (const int*)d_in[3];
  const int b = in_sizes[1];
  const int s = in_sizes[3];
  const int f = in_sizes[0] / b;
  float* out = (float*)d_out;

  char* p = (char*)d_ws;
  size_t used = 0;
  auto alloc = [&](size_t bytes) {
    char* r = p;
    size_t a = (bytes + 255) & ~(size_t)255;
    p += a; used += a;
    return r;
  };
  int* inv     = (int*)alloc((size_t)s * 4);
  int* labels  = (int*)alloc((size_t)b * 4);
  int* rank    = (int*)alloc((size_t)b * 4);
  float* invY  = (float*)alloc((size_t)s * 4);
  float* invZ  = (float*)alloc((size_t)b * 4);
  float* simL  = (float*)alloc((size_t)b * 4);

  const int nkc = f >> 5;                  // k-chunks of 32
  const int nrt = b / 128;                 // Z row tiles
  const int nct = (s + 159) / 160;         // Y col tiles (padded)
  const int rows_pad = nct * 160;
  const size_t zpan_sz = (size_t)nrt * nkc * 16384;
  const size_t ypan_sz = (size_t)nct * nkc * 20480;
  const size_t need = used + zpan_sz + ypan_sz + 1024;
  const bool use_pan = (ws_size >= need) && (b % 128 == 0) && (f % 512 == 0);

  hipMemsetAsync(rank, 0, (size_t)b * 4, stream);
  k_init_inv<<<(s + 255) / 256, 256, 0, stream>>>(inv, s);
  k_scatter<<<(s + 255) / 256, 256, 0, stream>>>(tyi, inv, s);
  k_labels<<<(b + 255) / 256, 256, 0, stream>>>(yi, inv, labels, b, s);

  if (use_pan) {
    char* Zpan = (char*)alloc(zpan_sz);
    char* Ypan = (char*)alloc(ypan_sz);
    k_packY<<<rows_pad / 4, 256, 0, stream>>>(Y, Ypan, invY, s, f, nkc);
    k_packZ<<<b / 4, 256, 0, stream>>>(Z, Y, labels, invY, Zpan, invZ, simL, f, nkc);
    dim3 grid(nrt, nct);  // x = row tile (fast) -> concurrent blocks share col tile
    k_gemm_rank_pan<<<grid, 256, 0, stream>>>(Zpan, Ypan, invZ, invY, simL,
                                              labels, rank, b, s, nkc);
  } else {
    k_ynorm<<<s, 256, 0, stream>>>(Y, invY, f);
    k_zrow<<<b, 256, 0, stream>>>(Z, Y, labels, invY, invZ, simL, f);
    dim3 grid((s + TNF - 1) / TNF, (b + TMF - 1) / TMF);
    k_gemm_rank_v2<<<grid, 256, 0, stream>>>(Z, Y, invZ, invY, simL, labels,
                                             rank, b, s, f);
  }
  k_final<<<1, 256, 0, stream>>>(rank, out, b);
}